// Round 1
// baseline (880.803 us; speedup 1.0000x reference)
//
#include <hip/hip_runtime.h>
#include <hip/hip_bf16.h>

// Problem constants
#define NB   64      // batch N
#define TT   12      // T
#define VV   256     // V (vertices)
#define CIN  64
#define COUT 64
#define VSQ  65536   // V*V

// ---------------------------------------------------------------------------
// K1: y[n,o,t,v] = sum_c x[n,c,t,v] * conv_w[o,c] + conv_b[o]
// block = (n*T + t), 256 threads (thread = v). y written into d_out's "out"
// region (same shape), later consumed+overwritten in-place by K3.
// ---------------------------------------------------------------------------
__global__ __launch_bounds__(256) void k1_conv(
    const float* __restrict__ x, const float* __restrict__ w,
    const float* __restrict__ b, float* __restrict__ y)
{
    const int nt = blockIdx.x;
    const int n  = nt / TT;
    const int t  = nt % TT;
    const int v  = threadIdx.x;

    __shared__ float xs[CIN][VV];   // 64 KiB
    const float* xp = x + ((long)n * CIN * TT + t) * VV;
    #pragma unroll 4
    for (int c = 0; c < CIN; ++c)
        xs[c][v] = xp[(long)c * TT * VV + v];
    __syncthreads();

    float* yp = y + ((long)n * COUT * TT + t) * VV + v;

    for (int o0 = 0; o0 < COUT; o0 += 16) {
        float acc[16];
        #pragma unroll
        for (int i = 0; i < 16; ++i) acc[i] = b[o0 + i];
        #pragma unroll 4
        for (int c = 0; c < CIN; ++c) {
            const float xv = xs[c][v];
            #pragma unroll
            for (int i = 0; i < 16; ++i)
                acc[i] += w[(o0 + i) * CIN + c] * xv;   // uniform -> s_load
        }
        #pragma unroll
        for (int i = 0; i < 16; ++i)
            yp[(long)(o0 + i) * TT * VV] = acc[i];
    }
}

// ---------------------------------------------------------------------------
// K2: Aw[n,c,v,w] = relu(W3 relu(W2 relu(W1 feats + b1) + b2) + b3) * mask
// One thread per (n,v,w) position. All weights are wave-uniform global loads
// -> scalar s_load pipe; intermediates h1[16]/h2[32] in VGPRs.
// ---------------------------------------------------------------------------
__global__ __launch_bounds__(256) void k2_mlp(
    const float* __restrict__ A,
    const float* __restrict__ w1, const float* __restrict__ b1,
    const float* __restrict__ w2, const float* __restrict__ b2,
    const float* __restrict__ w3, const float* __restrict__ b3,
    float* __restrict__ Aw)
{
    const long idx = (long)blockIdx.x * 256 + threadIdx.x;  // n*VSQ + v*V + w
    const int  n   = (int)(idx >> 16);
    const int  rem = (int)(idx & (VSQ - 1));

    const float* ap = A + ((long)n * 8 << 16) + rem;
    float f[7];
    #pragma unroll
    for (int c = 0; c < 7; ++c) f[c] = ap[(long)c << 16];
    const float m = ap[(long)7 << 16];

    float h1[16];
    #pragma unroll
    for (int o = 0; o < 16; ++o) {
        float acc = b1[o];
        #pragma unroll
        for (int k = 0; k < 7; ++k) acc += w1[o * 7 + k] * f[k];
        h1[o] = fmaxf(acc, 0.f);
    }

    float h2[32];
    #pragma unroll
    for (int o = 0; o < 32; ++o) {
        float acc = b2[o];
        #pragma unroll
        for (int k = 0; k < 16; ++k) acc += w2[o * 16 + k] * h1[k];
        h2[o] = fmaxf(acc, 0.f);
    }

    float* op = Aw + ((long)n * COUT << 16) + rem;
    #pragma unroll 4
    for (int o = 0; o < COUT; ++o) {
        float acc = b3[o];
        #pragma unroll
        for (int k = 0; k < 32; ++k) acc += w3[o * 32 + k] * h2[k];
        op[(long)o << 16] = fmaxf(acc, 0.f) * m;
    }
}

// ---------------------------------------------------------------------------
// K3: out[n,c,t,w] = sum_v y[n,c,t,v] * Aw[n,c,v,w]   (in-place over y)
// block = (n*COUT + c), 256 threads (thread = w). y tile staged in LDS before
// any global write -> in-place safe (block owns its (n,c) tile exclusively).
// ---------------------------------------------------------------------------
__global__ __launch_bounds__(256) void k3_einsum(
    const float* __restrict__ Aw, float* __restrict__ y_out)
{
    const int nc = blockIdx.x;          // n*64 + c
    const int w  = threadIdx.x;

    __shared__ float ys[TT][VV];        // 12 KiB
    const float* yp = y_out + (long)nc * TT * VV;
    #pragma unroll
    for (int t = 0; t < TT; ++t)
        ys[t][w] = yp[t * VV + w];      // coalesced
    __syncthreads();

    const float* awp = Aw + ((long)nc << 16) + w;
    float acc[TT];
    #pragma unroll
    for (int t = 0; t < TT; ++t) acc[t] = 0.f;

    for (int v = 0; v < VV; ++v) {
        const float aw = awp[(long)v * VV];   // coalesced across threads
        #pragma unroll
        for (int t = 0; t < TT; ++t)
            acc[t] += ys[t][v] * aw;          // ys: uniform broadcast read
    }

    float* op = y_out + (long)nc * TT * VV + w;
    #pragma unroll
    for (int t = 0; t < TT; ++t)
        op[t * VV] = acc[t];
}

// ---------------------------------------------------------------------------
extern "C" void kernel_launch(void* const* d_in, const int* in_sizes, int n_in,
                              void* d_out, int out_size, void* d_ws, size_t ws_size,
                              hipStream_t stream)
{
    const float* x      = (const float*)d_in[0];
    const float* A      = (const float*)d_in[1];
    const float* conv_w = (const float*)d_in[2];
    const float* conv_b = (const float*)d_in[3];
    const float* w1     = (const float*)d_in[4];
    const float* b1     = (const float*)d_in[5];
    const float* w2     = (const float*)d_in[6];
    const float* b2     = (const float*)d_in[7];
    const float* w3     = (const float*)d_in[8];
    const float* b3     = (const float*)d_in[9];

    float* out_y = (float*)d_out;                                   // (64,64,12,256)
    float* Aw    = (float*)d_out + (long)NB * COUT * TT * VV;       // (64,64,256,256)

    // K1: conv -> y (stored in out region)
    k1_conv<<<NB * TT, 256, 0, stream>>>(x, conv_w, conv_b, out_y);

    // K2: MLP + mask -> Aw
    k2_mlp<<<(NB * VSQ) / 256, 256, 0, stream>>>(A, w1, b1, w2, b2, w3, b3, Aw);

    // K3: einsum, in-place over y
    k3_einsum<<<NB * COUT, 256, 0, stream>>>(Aw, out_y);
}